// Round 3
// baseline (695.935 us; speedup 1.0000x reference)
//
#include <hip/hip_runtime.h>
#include <hip/hip_bf16.h>
#include <cstdint>

#define B_ 8
#define T_ 4096
#define D_ 768
#define H_ 12
#define M_ (B_*T_)          // 32768 rows
#define CHUNKS 64
#define CLEN 64             // CHUNKS*CLEN == T_
#define NCH (B_*H_*64)      // 6144 scan channels
#define KF 1536             // fused GEMM K  (x | x_prev)
#define NF 2304             // fused GEMM N  (r | k | v)
#define TP1 (T_+1)          // padded rows per batch (row 0 = zeros)

typedef __attribute__((ext_vector_type(8))) short bf16x8;
typedef __attribute__((ext_vector_type(4))) float f32x4;

static __device__ __forceinline__ unsigned short f2bf(float f) {
  __hip_bfloat16 h = __float2bfloat16(f);
  return __builtin_bit_cast(unsigned short, h);
}
static __device__ __forceinline__ float bf2f(unsigned short u) {
  unsigned v = ((unsigned)u) << 16;
  return __builtin_bit_cast(float, v);
}

static __device__ __forceinline__ void async16(const void* g, void* l) {
  __builtin_amdgcn_global_load_lds(
      (const __attribute__((address_space(1))) unsigned int*)g,
      (__attribute__((address_space(3))) unsigned int*)l, 16, 0, 0);
}

// ---------------- fallback: zero the output (ws too small diagnostic) ----------------
__global__ __launch_bounds__(256) void zero_out_kernel(float* __restrict__ out, size_t n4) {
  size_t gid = (size_t)blockIdx.x * 256 + threadIdx.x;
  if (gid < n4) *(float4*)(out + gid * 4) = make_float4(0.f, 0.f, 0.f, 0.f);
}

// ---------------- x -> padded bf16 [B, T+1, D], row 0 of each batch = zeros ----------------
__global__ __launch_bounds__(256) void xpad_kernel(
    const float* __restrict__ x, unsigned short* __restrict__ xp) {
  size_t gid = (size_t)blockIdx.x * 256 + threadIdx.x;
  size_t idx4 = gid * 4;                 // index into xpad (B*(T+1)*D)
  size_t row = idx4 / D_;
  int d = (int)(idx4 % D_);
  int b = (int)(row / TP1);
  int tt = (int)(row % TP1);             // 0 = zero row, else token tt-1
  ushort4 u = make_ushort4(0, 0, 0, 0);
  if (tt > 0) {
    float4 v = *(const float4*)(x + ((size_t)(b * T_ + tt - 1)) * D_ + d);
    u.x = f2bf(v.x); u.y = f2bf(v.y); u.z = f2bf(v.z); u.w = f2bf(v.w);
  }
  *(ushort4*)(xp + idx4) = u;
}

// ------- build Wcat[NF, KF] bf16: rows 0..767=Wr, 768..1535=Wk, 1536..2303=Wv -------
// col j<768:  W[n, j] * mix[j]     (multiplies the current-token half)
// col j>=768: W[n, j-768] * (1-mix[j-768])   (previous-token half)
__global__ __launch_bounds__(256) void wfold_kernel(
    const float* __restrict__ Wr, const float* __restrict__ Wk,
    const float* __restrict__ Wv,
    const float* __restrict__ tmr, const float* __restrict__ tmk,
    const float* __restrict__ tmv, unsigned short* __restrict__ Wcat) {
  size_t gid = (size_t)blockIdx.x * 256 + threadIdx.x;
  size_t idx4 = gid * 4;                 // into Wcat (NF*KF)
  int j = (int)(idx4 % KF);
  int n = (int)(idx4 / KF);
  int which = n / D_;                    // 0=r 1=k 2=v
  int nn = n % D_;
  const float* W = (which == 0) ? Wr : (which == 1) ? Wk : Wv;
  const float* mx = (which == 0) ? tmr : (which == 1) ? tmk : tmv;
  int cur = (j < D_);
  int jj = cur ? j : j - D_;
  float4 wv = *(const float4*)(W + (size_t)nn * D_ + jj);
  float4 mv = *(const float4*)(mx + jj);
  float4 f;
  f.x = cur ? mv.x : (1.f - mv.x);
  f.y = cur ? mv.y : (1.f - mv.y);
  f.z = cur ? mv.z : (1.f - mv.z);
  f.w = cur ? mv.w : (1.f - mv.w);
  ushort4 u;
  u.x = f2bf(wv.x * f.x); u.y = f2bf(wv.y * f.y);
  u.z = f2bf(wv.z * f.z); u.w = f2bf(wv.w * f.w);
  *(ushort4*)(Wcat + idx4) = u;
}

// ---------------- W_o fp32 -> bf16 ----------------
__global__ __launch_bounds__(256) void woconv_kernel(
    const float* __restrict__ w, unsigned short* __restrict__ o) {
  size_t gid = (size_t)blockIdx.x * 256 + threadIdx.x;
  size_t idx4 = gid * 4;
  float4 v = *(const float4*)(w + idx4);
  ushort4 u;
  u.x = f2bf(v.x); u.y = f2bf(v.y); u.z = f2bf(v.z); u.w = f2bf(v.w);
  *(ushort4*)(o + idx4) = u;
}

// ---- fused GEMM: RKV[M, NF] = [x | x_prev] @ Wcat^T.  sigmoid on n<768.
//      A comes from xpad [B, T+1, D]: k<768 -> row t+1 (current), k>=768 -> row t (prev).
//      Flat grid 4608, XCD-swizzled: all 18 n-tiles of an m-strip on one XCD.
__global__ __launch_bounds__(256) void gemm_fused(
    const unsigned short* __restrict__ xpad,
    const unsigned short* __restrict__ Wcat,
    unsigned short* __restrict__ RKV) {
  __shared__ __align__(16) unsigned short smem[128 * 128];   // 32 KB
  unsigned short* As = smem;              // 128 rows x 32 k
  unsigned short* Bs = smem + 128 * 32;

  const int flat = blockIdx.x;
  const int xcd = flat & 7;
  const int j8 = flat >> 3;              // 0..575
  const int strip = xcd * 32 + j8 / 18;  // m-strip 0..255
  const int ntile = j8 % 18;
  const int m0 = strip * 128, n0 = ntile * 128;
  const int b = strip >> 5;              // 4096/128=32 strips per batch
  const int tbase = (strip & 31) * 128;  // t of first row in strip

  const int tid = threadIdx.x;
  const int wave = tid >> 6, lane = tid & 63;
  const int quad = lane >> 4, l16 = lane & 15;
  const int wm = (wave & 1) * 64, wn = (wave >> 1) * 64;

  const size_t bbase = (size_t)b * TP1 * D_;

  f32x4 acc[4][4] = {};

  for (int kb = 0; kb < KF; kb += 32) {
    __syncthreads();
#pragma unroll
    for (int jj = 0; jj < 2; ++jj) {
      int chunk = wave * 128 + jj * 64 + lane;   // 0..511, 16B each
      int row = chunk >> 2, kc = chunk & 3;
      int kg = kb + kc * 8;
      int cur = (kg < D_);
      int kk = cur ? kg : kg - D_;
      const unsigned short* ga =
          xpad + bbase + ((size_t)(tbase + row + cur)) * D_ + kk;
      async16(ga, &As[chunk * 8]);
      const unsigned short* gb = Wcat + ((size_t)(n0 + row)) * KF + kg;
      async16(gb, &Bs[chunk * 8]);
    }
    __syncthreads();

    bf16x8 a[4], bfr[4];
#pragma unroll
    for (int i = 0; i < 4; ++i)
      a[i] = *(const bf16x8*)&As[(wm + i * 16 + l16) * 32 + quad * 8];
#pragma unroll
    for (int i = 0; i < 4; ++i)
      bfr[i] = *(const bf16x8*)&Bs[(wn + i * 16 + l16) * 32 + quad * 8];
#pragma unroll
    for (int i = 0; i < 4; ++i)
#pragma unroll
      for (int jj = 0; jj < 4; ++jj)
        acc[i][jj] = __builtin_amdgcn_mfma_f32_16x16x32_bf16(a[i], bfr[jj], acc[i][jj], 0, 0, 0);
  }

  // ---- epilogue: stage bf16 tile in LDS, write full-line 16B chunks ----
  const int do_sig = (ntile < 6);
  __syncthreads();                       // last tile's ds_reads done before overwrite
#pragma unroll
  for (int i = 0; i < 4; ++i)
#pragma unroll
    for (int jj = 0; jj < 4; ++jj)
#pragma unroll
      for (int r = 0; r < 4; ++r) {
        float v = acc[i][jj][r];
        if (do_sig) v = 1.f / (1.f + __expf(-v));
        smem[(wm + i * 16 + quad * 4 + r) * 128 + wn + jj * 16 + l16] = f2bf(v);
      }
  __syncthreads();
#pragma unroll
  for (int s = 0; s < 8; ++s) {
    int cid = s * 256 + tid;             // 2048 chunks of 16B
    int row = cid >> 4, c8 = cid & 15;
    bf16x8 val = *(const bf16x8*)&smem[row * 128 + c8 * 8];
    *(bf16x8*)(RKV + (size_t)(m0 + row) * NF + n0 + c8 * 8) = val;
  }
}

// ---- Wo GEMM: out[M, D] fp32 = Yb[M, D] @ Wo^T.  Flat grid 1536, XCD-swizzled. ----
__global__ __launch_bounds__(256) void gemm_wo(
    const unsigned short* __restrict__ A,
    const unsigned short* __restrict__ Bw,
    float* __restrict__ C) {
  __shared__ __align__(16) unsigned short As[128 * 32];
  __shared__ __align__(16) unsigned short Bs[128 * 32];
  const int flat = blockIdx.x;
  const int xcd = flat & 7;
  const int j8 = flat >> 3;              // 0..191
  const int strip = xcd * 32 + j8 / 6;
  const int ntile = j8 % 6;
  const int m0 = strip * 128, n0 = ntile * 128;

  const int tid = threadIdx.x;
  const int wave = tid >> 6, lane = tid & 63;
  const int quad = lane >> 4, l16 = lane & 15;
  const int wm = (wave & 1) * 64, wn = (wave >> 1) * 64;

  f32x4 acc[4][4] = {};

  for (int kb = 0; kb < D_; kb += 32) {
    __syncthreads();
#pragma unroll
    for (int jj = 0; jj < 2; ++jj) {
      int chunk = wave * 128 + jj * 64 + lane;
      int row = chunk >> 2, kc = chunk & 3;
      const unsigned short* ga = A + ((size_t)(m0 + row)) * D_ + kb + kc * 8;
      async16(ga, &As[chunk * 8]);
      const unsigned short* gb = Bw + ((size_t)(n0 + row)) * D_ + kb + kc * 8;
      async16(gb, &Bs[chunk * 8]);
    }
    __syncthreads();

    bf16x8 a[4], bfr[4];
#pragma unroll
    for (int i = 0; i < 4; ++i)
      a[i] = *(const bf16x8*)&As[(wm + i * 16 + l16) * 32 + quad * 8];
#pragma unroll
    for (int i = 0; i < 4; ++i)
      bfr[i] = *(const bf16x8*)&Bs[(wn + i * 16 + l16) * 32 + quad * 8];
#pragma unroll
    for (int i = 0; i < 4; ++i)
#pragma unroll
      for (int jj = 0; jj < 4; ++jj)
        acc[i][jj] = __builtin_amdgcn_mfma_f32_16x16x32_bf16(a[i], bfr[jj], acc[i][jj], 0, 0, 0);
  }

#pragma unroll
  for (int i = 0; i < 4; ++i) {
    int rowb = m0 + wm + i * 16 + quad * 4;
#pragma unroll
    for (int jj = 0; jj < 4; ++jj) {
      int col = n0 + wn + jj * 16 + l16;
#pragma unroll
      for (int r = 0; r < 4; ++r)
        C[(size_t)(rowb + r) * D_ + col] = acc[i][jj][r];
    }
  }
}

// ---------------- WKV pass 1: per-chunk local scan over RKV ----------------
__global__ __launch_bounds__(256) void wkv_pass1(
    const unsigned short* __restrict__ RKV, const float* __restrict__ td,
    float* __restrict__ sumN, float* __restrict__ sumD) {
  int gid = blockIdx.x * 256 + threadIdx.x;     // ((c*B + b)*H + h)*64 + k
  int k = gid & 63;
  int h = (gid >> 6) % H_;
  int tmp = (gid >> 6) / H_;
  int b = tmp % B_;
  int c = tmp / B_;
  float w = __expf(-__expf(td[h * 64 + k]));
  const unsigned short* Kp =
      RKV + ((size_t)(b * T_ + c * CLEN)) * NF + D_ + h * 64 + k;   // K column
  float num = 0.f, den = 0.f;
#pragma unroll 8
  for (int i = 0; i < CLEN; ++i) {
    float kk = bf2f(Kp[(size_t)i * NF]);
    float vv = bf2f(Kp[(size_t)i * NF + D_]);   // V column = K + 768
    float ek = __expf(kk);
    num = num * w + ek * vv;
    den = den * w + ek;
  }
  sumN[gid] = num;
  sumD[gid] = den;
}

// ---- WKV pass 2: inter-chunk exclusive prefix IN PLACE over sumN/sumD + zero gstats ----
__global__ __launch_bounds__(256) void wkv_pass2(
    float* __restrict__ sumN, float* __restrict__ sumD,
    const float* __restrict__ td, float* __restrict__ gstats) {
  int tid = blockIdx.x * 256 + threadIdx.x;     // < 6144
  if (blockIdx.x == 0 && threadIdx.x < 192) gstats[threadIdx.x] = 0.f;
  int k = tid & 63;
  int h = (tid >> 6) % H_;
  float w = __expf(-__expf(td[h * 64 + k]));
  float wL = w;
#pragma unroll
  for (int i = 0; i < 6; ++i) wL *= wL;         // w^64
  float n = 0.f, d = 0.f;
  for (int c = 0; c < CHUNKS; ++c) {
    int j = c * NCH + tid;
    float sn = sumN[j], sd = sumD[j];
    sumN[j] = n; sumD[j] = d;                   // now exclusive prefix (carry-in)
    n = n * wL + sn;
    d = d * wL + sd;
  }
}

// --- WKV pass 3: wkv + y=r*wkv (in place over RKV r-cols) + GN partial sums ---
__global__ __launch_bounds__(256) void wkv_pass3(
    unsigned short* __restrict__ RKV,
    const float* __restrict__ td, const float* __restrict__ tf,
    const float* __restrict__ prefN, const float* __restrict__ prefD,
    float* __restrict__ gsum, float* __restrict__ gsq) {
  int gid = blockIdx.x * 256 + threadIdx.x;
  int k = gid & 63;
  int h = (gid >> 6) % H_;
  int tmp = (gid >> 6) / H_;
  int b = tmp % B_;
  int c = tmp / B_;
  float w = __expf(-__expf(td[h * 64 + k]));
  float eu = __expf(tf[h * 64 + k]);
  float num = prefN[gid], den = prefD[gid];
  unsigned short* Rp = RKV + ((size_t)(b * T_ + c * CLEN)) * NF + h * 64 + k;
  float s1 = 0.f, s2 = 0.f;
#pragma unroll 4
  for (int i = 0; i < CLEN; ++i) {
    size_t off = (size_t)i * NF;
    float rr = bf2f(Rp[off]);
    float kk = bf2f(Rp[off + D_]);
    float vv = bf2f(Rp[off + 2 * D_]);
    float ek = __expf(kk);
    float wkv = (num + eu * ek * vv) / (den + eu * ek + 1e-9f);
    unsigned short ybf = f2bf(rr * wkv);
    Rp[off] = ybf;
    float y = bf2f(ybf);               // stats on the stored (rounded) value
    s1 += y; s2 += y * y;
    num = num * w + ek * vv;
    den = den * w + ek;
  }
#pragma unroll
  for (int off = 32; off; off >>= 1) {
    s1 += __shfl_down(s1, off);
    s2 += __shfl_down(s2, off);
  }
  if (k == 0) {
    atomicAdd(&gsum[b * H_ + h], s1);
    atomicAdd(&gsq [b * H_ + h], s2);
  }
}

// ------- GroupNorm normalize (reads RKV r-cols) -> compact bf16 Yb[M, D] -------
__global__ __launch_bounds__(256) void gn_kernel(
    const unsigned short* __restrict__ RKV, const float* __restrict__ gsum,
    const float* __restrict__ gsq, const float* __restrict__ gw,
    const float* __restrict__ gb, unsigned short* __restrict__ Yb) {
  size_t gid = (size_t)blockIdx.x * 256 + threadIdx.x;
  size_t idx4 = gid * 4;                 // into Yb (M*D)
  int d = (int)(idx4 % D_);
  size_t row = idx4 / D_;
  int b = (int)(row >> 12);              // T = 4096
  int h = d >> 6;
  int g = b * H_ + h;
  const float inv = 1.f / (float)(T_ * 64);
  float mean = gsum[g] * inv;
  float var = gsq[g] * inv - mean * mean;
  float rstd = rsqrtf(var + 1e-5f);
  ushort4 yu = *(const ushort4*)(RKV + row * NF + d);
  float4 wv = *(const float4*)(gw + d);
  float4 bv = *(const float4*)(gb + d);
  ushort4 o;
  o.x = f2bf((bf2f(yu.x) - mean) * rstd * wv.x + bv.x);
  o.y = f2bf((bf2f(yu.y) - mean) * rstd * wv.y + bv.y);
  o.z = f2bf((bf2f(yu.z) - mean) * rstd * wv.z + bv.z);
  o.w = f2bf((bf2f(yu.w) - mean) * rstd * wv.w + bv.w);
  *(ushort4*)(Yb + idx4) = o;
}

extern "C" void kernel_launch(void* const* d_in, const int* in_sizes, int n_in,
                              void* d_out, int out_size, void* d_ws, size_t ws_size,
                              hipStream_t stream) {
  (void)in_sizes; (void)n_in; (void)out_size;
  const float* x   = (const float*)d_in[0];
  const float* tmr = (const float*)d_in[1];
  const float* tmk = (const float*)d_in[2];
  const float* tmv = (const float*)d_in[3];
  const float* td  = (const float*)d_in[4];
  const float* tf  = (const float*)d_in[5];
  const float* Wr  = (const float*)d_in[6];
  const float* Wk  = (const float*)d_in[7];
  const float* Wv  = (const float*)d_in[8];
  const float* Wo  = (const float*)d_in[9];
  const float* gw  = (const float*)d_in[10];
  const float* gb  = (const float*)d_in[11];
  float* out = (float*)d_out;

  constexpr size_t XPAD_E = (size_t)B_ * TP1 * D_;   // 25,171,968
  constexpr size_t RKV_E  = (size_t)M_ * NF;         // 75,497,472
  constexpr size_t WCAT_E = (size_t)NF * KF;         //  3,538,944
  constexpr size_t WO_E   = (size_t)D_ * D_;         //    589,824
  constexpr size_t MD     = (size_t)M_ * D_;
  constexpr size_t NEED   = 2 * (XPAD_E + RKV_E + WCAT_E + WO_E);   // ~209.6 MB
  if (ws_size < NEED) {
    zero_out_kernel<<<(int)((MD / 4 + 255) / 256), 256, 0, stream>>>(out, MD / 4);
    return;
  }

  char* ws = (char*)d_ws;
  unsigned short* Xp   = (unsigned short*)ws; ws += XPAD_E * 2;
  unsigned short* RKV  = (unsigned short*)ws; ws += RKV_E * 2;
  unsigned short* Wcat = (unsigned short*)ws; ws += WCAT_E * 2;
  unsigned short* Wob  = (unsigned short*)ws; ws += WO_E * 2;
  // aliases onto dead regions (dataflow-checked):
  unsigned short* Yb = Xp;                      // xpad dead after gemm_fused
  float* sumN   = (float*)Wcat;                 // Wcat dead after gemm_fused
  float* sumD   = sumN + (size_t)CHUNKS * NCH;  // 2 x 1.57 MB + 768 B < 7.08 MB
  float* gstats = sumD + (size_t)CHUNKS * NCH;

  xpad_kernel <<<(int)(XPAD_E / 1024), 256, 0, stream>>>(x, Xp);
  wfold_kernel<<<(int)(WCAT_E / 1024), 256, 0, stream>>>(Wr, Wk, Wv, tmr, tmk, tmv, Wcat);
  woconv_kernel<<<(int)(WO_E / 1024), 256, 0, stream>>>(Wo, Wob);

  gemm_fused<<<8 * 32 * 18, 256, 0, stream>>>(Xp, Wcat, RKV);

  wkv_pass1<<<(CHUNKS * NCH) / 256, 256, 0, stream>>>(RKV, td, sumN, sumD);
  wkv_pass2<<<NCH / 256, 256, 0, stream>>>(sumN, sumD, td, gstats);
  wkv_pass3<<<(CHUNKS * NCH) / 256, 256, 0, stream>>>(RKV, td, tf, sumN, sumD,
                                                      gstats, gstats + 96);
  gn_kernel<<<(int)(MD / 1024), 256, 0, stream>>>(RKV, gstats, gstats + 96, gw, gb, Yb);

  gemm_wo<<<8 * 32 * 6, 256, 0, stream>>>(Yb, Wob, out);
}

// Round 5
// 585.838 us; speedup vs baseline: 1.1879x; 1.1879x over previous
//
#include <hip/hip_runtime.h>
#include <hip/hip_bf16.h>
#include <cstdint>

#define B_ 8
#define T_ 4096
#define D_ 768
#define H_ 12
#define M_ (B_*T_)          // 32768 rows
#define CHUNKS 64
#define CLEN 64             // CHUNKS*CLEN == T_
#define NCH (B_*H_*64)      // 6144 scan channels
#define NF 2304             // RKV row stride (r|k|v)
#define WELEM (D_*D_)       // 589824

typedef __attribute__((ext_vector_type(8))) short bf16x8;
typedef __attribute__((ext_vector_type(4))) float f32x4;

static __device__ __forceinline__ unsigned short f2bf(float f) {
  __hip_bfloat16 h = __float2bfloat16(f);
  return __builtin_bit_cast(unsigned short, h);
}
static __device__ __forceinline__ float bf2f(unsigned short u) {
  unsigned v = ((unsigned)u) << 16;
  return __builtin_bit_cast(float, v);
}

static __device__ __forceinline__ void async16(const void* g, void* l) {
  __builtin_amdgcn_global_load_lds(
      (const __attribute__((address_space(1))) unsigned int*)g,
      (__attribute__((address_space(3))) unsigned int*)l, 16, 0, 0);
}

// ---------------- fallback: zero the output (ws too small diagnostic) ----------------
__global__ __launch_bounds__(256) void zero_out_kernel(float* __restrict__ out, size_t n4) {
  size_t gid = (size_t)blockIdx.x * 256 + threadIdx.x;
  if (gid < n4) *(float4*)(out + gid * 4) = make_float4(0.f, 0.f, 0.f, 0.f);
}

// ---------------- one token-shift mix: o = x*m + x_prev*(1-m)  (bf16 out) ----------------
__global__ __launch_bounds__(256) void mix_one_kernel(
    const float* __restrict__ x, const float* __restrict__ tm,
    unsigned short* __restrict__ o) {
  size_t gid = (size_t)blockIdx.x * 256 + threadIdx.x;
  size_t idx4 = gid * 4;
  int d = (int)(idx4 % D_);
  size_t row = idx4 / D_;
  int t = (int)(row & (T_ - 1));
  float4 xc = *(const float4*)(x + idx4);
  float4 xp = make_float4(0.f, 0.f, 0.f, 0.f);
  if (t > 0) xp = *(const float4*)(x + idx4 - D_);
  float4 m = *(const float4*)(tm + d);
  ushort4 u;
  u.x = f2bf(xp.x + m.x * (xc.x - xp.x));
  u.y = f2bf(xp.y + m.y * (xc.y - xp.y));
  u.z = f2bf(xp.z + m.z * (xc.z - xp.z));
  u.w = f2bf(xp.w + m.w * (xc.w - xp.w));
  *(ushort4*)(o + idx4) = u;
}

// ---------------- 4 weights fp32 -> bf16 (keeps [out,in] layout) ----------------
__global__ __launch_bounds__(256) void wconv_kernel(
    const float* __restrict__ a, const float* __restrict__ b,
    const float* __restrict__ c, const float* __restrict__ d,
    unsigned short* __restrict__ o) {
  size_t gid = (size_t)blockIdx.x * 256 + threadIdx.x;
  size_t idx4 = gid * 4;
  size_t mi = idx4 / WELEM;
  size_t off = idx4 % WELEM;
  const float* src = (mi == 0) ? a : (mi == 1) ? b : (mi == 2) ? c : d;
  float4 v = *(const float4*)(src + off);
  ushort4 u;
  u.x = f2bf(v.x); u.y = f2bf(v.y); u.z = f2bf(v.z); u.w = f2bf(v.w);
  *(ushort4*)(o + idx4) = u;
}

// ==== GEMM: C[M, 768] = A[M,768] @ Bw[768,768]^T, double-buffered LDS staging.
//      SIG: sigmoid epilogue.  OBF: 1 = bf16 out (LDS-staged, padded), 0 = fp32 direct.
//      C written at row*ldc + col0 + n.  Grid 1536 flat, XCD-grouped (6 n-tiles/strip).
#define EPI_LD 136    // padded epilogue stride (shorts); 272 B -> 2-way banks (free)
template<int SIG, int OBF>
__global__ __launch_bounds__(256) void gemm_bt(
    const unsigned short* __restrict__ A,
    const unsigned short* __restrict__ Bw,
    void* __restrict__ Cv, int ldc, int col0) {
  // staging: 2 x (As 4096 + Bs 4096) shorts = 32 KB; epilogue (OBF): 128x136 = 34.8 KB
  constexpr int SMEM = OBF ? (128 * EPI_LD) : 16384;
  __shared__ __align__(16) unsigned short smem[SMEM < 16384 ? 16384 : SMEM];

  const int flat = blockIdx.x;
  const int xcd = flat & 7;
  const int s = flat >> 3;               // 0..191
  const int strip = xcd * 32 + s / 6;    // 0..255: all 6 n-tiles of a strip on one XCD
  const int nt = s % 6;
  const int m0 = strip * 128, n0 = nt * 128;

  const int tid = threadIdx.x;
  const int wave = tid >> 6, lane = tid & 63;
  const int quad = lane >> 4, l16 = lane & 15;
  const int wm = (wave & 1) * 64, wn = (wave >> 1) * 64;

  // per-thread staging task: 2 A-chunks + 2 B-chunks of 16 B (4 async16/iter)
  const int ch0 = wave * 128 + lane;           // j=0 chunk
  const int ch1 = ch0 + 64;                    // j=1 chunk
  const int r0 = ch0 >> 2, k0c = (ch0 & 3) * 8;
  const int r1 = ch1 >> 2, k1c = (ch1 & 3) * 8;
  const unsigned short* ga0 = A  + ((size_t)(m0 + r0)) * D_ + k0c;
  const unsigned short* ga1 = A  + ((size_t)(m0 + r1)) * D_ + k1c;
  const unsigned short* gb0 = Bw + ((size_t)(n0 + r0)) * D_ + k0c;
  const unsigned short* gb1 = Bw + ((size_t)(n0 + r1)) * D_ + k1c;

  f32x4 acc[4][4] = {};

  // preload k-block 0 into buf 0
  {
    unsigned short* As = smem;          // buf0: As[0..4095], Bs[4096..8191]
    unsigned short* Bs = smem + 4096;
    async16(ga0, &As[ch0 * 8]);
    async16(ga1, &As[ch1 * 8]);
    async16(gb0, &Bs[ch0 * 8]);
    async16(gb1, &Bs[ch1 * 8]);
  }
  asm volatile("s_waitcnt vmcnt(0)" ::: "memory");
  asm volatile("s_barrier" ::: "memory");

  const int NI = D_ / 32;   // 24
  for (int i = 0; i < NI; ++i) {
    const int cb = i & 1;
    if (i + 1 < NI) {
      // prefetch next k-block into the other buffer (its previous contents were
      // consumed at iter i-1; trailing barrier of i-1 guards the overwrite)
      const int kb = (i + 1) * 32;
      unsigned short* As = smem + (cb ^ 1) * 8192;
      unsigned short* Bs = As + 4096;
      async16(ga0 + kb, &As[ch0 * 8]);
      async16(ga1 + kb, &As[ch1 * 8]);
      async16(gb0 + kb, &Bs[ch0 * 8]);
      async16(gb1 + kb, &Bs[ch1 * 8]);
      // wait for iter-i's 4 loads (leave the 4 just issued in flight)
      asm volatile("s_waitcnt vmcnt(4)" ::: "memory");
    } else {
      asm volatile("s_waitcnt vmcnt(0)" ::: "memory");
    }
    asm volatile("s_barrier" ::: "memory");   // all threads' iter-i DMA visible

    const unsigned short* As = smem + cb * 8192;
    const unsigned short* Bs = As + 4096;
    bf16x8 a[4], b[4];
#pragma unroll
    for (int ii = 0; ii < 4; ++ii)
      a[ii] = *(const bf16x8*)&As[(wm + ii * 16 + l16) * 32 + quad * 8];
#pragma unroll
    for (int ii = 0; ii < 4; ++ii)
      b[ii] = *(const bf16x8*)&Bs[(wn + ii * 16 + l16) * 32 + quad * 8];
#pragma unroll
    for (int ii = 0; ii < 4; ++ii)
#pragma unroll
      for (int jj = 0; jj < 4; ++jj)
        acc[ii][jj] = __builtin_amdgcn_mfma_f32_16x16x32_bf16(a[ii], b[jj], acc[ii][jj], 0, 0, 0);

    asm volatile("s_barrier" ::: "memory");   // reads of buf cb done before overwrite
  }

  if (OBF) {
    // stage bf16 tile in LDS (padded stride), write out as 16-B row chunks
    __syncthreads();
#pragma unroll
    for (int ii = 0; ii < 4; ++ii)
#pragma unroll
      for (int jj = 0; jj < 4; ++jj)
#pragma unroll
        for (int r = 0; r < 4; ++r) {
          float v = acc[ii][jj][r];
          if (SIG) v = 1.f / (1.f + __expf(-v));
          smem[(wm + ii * 16 + quad * 4 + r) * EPI_LD + wn + jj * 16 + l16] = f2bf(v);
        }
    __syncthreads();
    unsigned short* C = (unsigned short*)Cv;
#pragma unroll
    for (int sdx = 0; sdx < 8; ++sdx) {
      int cid = sdx * 256 + tid;            // 2048 chunks of 16 B
      int row = cid >> 4, c8 = cid & 15;
      bf16x8 val = *(const bf16x8*)&smem[row * EPI_LD + c8 * 8];
      *(bf16x8*)(C + (size_t)(m0 + row) * ldc + col0 + n0 + c8 * 8) = val;  // FIXED: + n0
    }
  } else {
    float* C = (float*)Cv;
#pragma unroll
    for (int ii = 0; ii < 4; ++ii) {
      int rowb = m0 + wm + ii * 16 + quad * 4;
#pragma unroll
      for (int jj = 0; jj < 4; ++jj) {
        int col = col0 + n0 + wn + jj * 16 + l16;
#pragma unroll
        for (int r = 0; r < 4; ++r) {
          float v = acc[ii][jj][r];
          if (SIG) v = 1.f / (1.f + __expf(-v));
          C[(size_t)(rowb + r) * ldc + col] = v;
        }
      }
    }
  }
}

// ---------------- WKV pass 1: per-chunk local scan over RKV ----------------
__global__ __launch_bounds__(256) void wkv_pass1(
    const unsigned short* __restrict__ RKV, const float* __restrict__ td,
    float* __restrict__ sumN, float* __restrict__ sumD) {
  int gid = blockIdx.x * 256 + threadIdx.x;     // ((c*B + b)*H + h)*64 + k
  int k = gid & 63;
  int h = (gid >> 6) % H_;
  int tmp = (gid >> 6) / H_;
  int b = tmp % B_;
  int c = tmp / B_;
  float w = __expf(-__expf(td[h * 64 + k]));
  const unsigned short* Kp =
      RKV + ((size_t)(b * T_ + c * CLEN)) * NF + D_ + h * 64 + k;   // K column
  float num = 0.f, den = 0.f;
#pragma unroll 8
  for (int i = 0; i < CLEN; ++i) {
    float kk = bf2f(Kp[(size_t)i * NF]);
    float vv = bf2f(Kp[(size_t)i * NF + D_]);   // V column = K + 768
    float ek = __expf(kk);
    num = num * w + ek * vv;
    den = den * w + ek;
  }
  sumN[gid] = num;
  sumD[gid] = den;
}

// ---- WKV pass 2: inter-chunk exclusive prefix IN PLACE over sumN/sumD + zero gstats ----
__global__ __launch_bounds__(256) void wkv_pass2(
    float* __restrict__ sumN, float* __restrict__ sumD,
    const float* __restrict__ td, float* __restrict__ gstats) {
  int tid = blockIdx.x * 256 + threadIdx.x;     // < 6144
  if (blockIdx.x == 0 && threadIdx.x < 192) gstats[threadIdx.x] = 0.f;
  int k = tid & 63;
  int h = (tid >> 6) % H_;
  float w = __expf(-__expf(td[h * 64 + k]));
  float wL = w;
#pragma unroll
  for (int i = 0; i < 6; ++i) wL *= wL;         // w^64
  float n = 0.f, d = 0.f;
  for (int c = 0; c < CHUNKS; ++c) {
    int j = c * NCH + tid;
    float sn = sumN[j], sd = sumD[j];
    sumN[j] = n; sumD[j] = d;                   // now exclusive prefix (carry-in)
    n = n * wL + sn;
    d = d * wL + sd;
  }
}

// --- WKV pass 3: wkv + y=r*wkv (in place over RKV r-cols) + GN partial sums ---
__global__ __launch_bounds__(256) void wkv_pass3(
    unsigned short* __restrict__ RKV,
    const float* __restrict__ td, const float* __restrict__ tf,
    const float* __restrict__ prefN, const float* __restrict__ prefD,
    float* __restrict__ gsum, float* __restrict__ gsq) {
  int gid = blockIdx.x * 256 + threadIdx.x;
  int k = gid & 63;
  int h = (gid >> 6) % H_;
  int tmp = (gid >> 6) / H_;
  int b = tmp % B_;
  int c = tmp / B_;
  float w = __expf(-__expf(td[h * 64 + k]));
  float eu = __expf(tf[h * 64 + k]);
  float num = prefN[gid], den = prefD[gid];
  unsigned short* Rp = RKV + ((size_t)(b * T_ + c * CLEN)) * NF + h * 64 + k;
  float s1 = 0.f, s2 = 0.f;
#pragma unroll 4
  for (int i = 0; i < CLEN; ++i) {
    size_t off = (size_t)i * NF;
    float rr = bf2f(Rp[off]);
    float kk = bf2f(Rp[off + D_]);
    float vv = bf2f(Rp[off + 2 * D_]);
    float ek = __expf(kk);
    float wkv = (num + eu * ek * vv) / (den + eu * ek + 1e-9f);
    unsigned short ybf = f2bf(rr * wkv);
    Rp[off] = ybf;
    float y = bf2f(ybf);               // stats on the stored (rounded) value
    s1 += y; s2 += y * y;
    num = num * w + ek * vv;
    den = den * w + ek;
  }
#pragma unroll
  for (int off = 32; off; off >>= 1) {
    s1 += __shfl_down(s1, off);
    s2 += __shfl_down(s2, off);
  }
  if (k == 0) {
    atomicAdd(&gsum[b * H_ + h], s1);
    atomicAdd(&gsq [b * H_ + h], s2);
  }
}

// ------- GroupNorm normalize (reads RKV r-cols) -> compact bf16 Yb[M, D] -------
__global__ __launch_bounds__(256) void gn_kernel(
    const unsigned short* __restrict__ RKV, const float* __restrict__ gsum,
    const float* __restrict__ gsq, const float* __restrict__ gw,
    const float* __restrict__ gb, unsigned short* __restrict__ Yb) {
  size_t gid = (size_t)blockIdx.x * 256 + threadIdx.x;
  size_t idx4 = gid * 4;                 // into Yb (M*D)
  int d = (int)(idx4 % D_);
  size_t row = idx4 / D_;
  int b = (int)(row >> 12);              // T = 4096
  int h = d >> 6;
  int g = b * H_ + h;
  const float inv = 1.f / (float)(T_ * 64);
  float mean = gsum[g] * inv;
  float var = gsq[g] * inv - mean * mean;
  float rstd = rsqrtf(var + 1e-5f);
  ushort4 yu = *(const ushort4*)(RKV + row * NF + d);
  float4 wv = *(const float4*)(gw + d);
  float4 bv = *(const float4*)(gb + d);
  ushort4 o;
  o.x = f2bf((bf2f(yu.x) - mean) * rstd * wv.x + bv.x);
  o.y = f2bf((bf2f(yu.y) - mean) * rstd * wv.y + bv.y);
  o.z = f2bf((bf2f(yu.z) - mean) * rstd * wv.z + bv.z);
  o.w = f2bf((bf2f(yu.w) - mean) * rstd * wv.w + bv.w);
  *(ushort4*)(Yb + idx4) = o;
}

extern "C" void kernel_launch(void* const* d_in, const int* in_sizes, int n_in,
                              void* d_out, int out_size, void* d_ws, size_t ws_size,
                              hipStream_t stream) {
  (void)in_sizes; (void)n_in; (void)out_size;
  const float* x   = (const float*)d_in[0];
  const float* tmr = (const float*)d_in[1];
  const float* tmk = (const float*)d_in[2];
  const float* tmv = (const float*)d_in[3];
  const float* td  = (const float*)d_in[4];
  const float* tf  = (const float*)d_in[5];
  const float* Wr  = (const float*)d_in[6];
  const float* Wk  = (const float*)d_in[7];
  const float* Wv  = (const float*)d_in[8];
  const float* Wo  = (const float*)d_in[9];
  const float* gw  = (const float*)d_in[10];
  const float* gb  = (const float*)d_in[11];
  float* out = (float*)d_out;

  constexpr size_t MD    = (size_t)M_ * D_;          // 25,165,824
  constexpr size_t RKV_E = (size_t)M_ * NF;          // 75,497,472
  constexpr size_t NEED  = MD * 2                    // mixbuf (reused r->k->v, then Yb)
                         + RKV_E * 2                 // RKV
                         + (size_t)4 * WELEM * 2     // Wb (r,k,v,o)
                         + 2 * ((size_t)CHUNKS * NCH * 4)  // sumN/sumD
                         + 1024;                     // gstats       => ~209.2 MB
  if (ws_size < NEED) {
    zero_out_kernel<<<(int)((MD / 4 + 255) / 256), 256, 0, stream>>>(out, MD / 4);
    return;
  }

  char* ws = (char*)d_ws;
  unsigned short* mixb = (unsigned short*)ws; ws += MD * 2;
  unsigned short* RKV  = (unsigned short*)ws; ws += RKV_E * 2;
  unsigned short* Wb   = (unsigned short*)ws; ws += (size_t)4 * WELEM * 2;
  float* sumN   = (float*)ws; ws += (size_t)CHUNKS * NCH * 4;
  float* sumD   = (float*)ws; ws += (size_t)CHUNKS * NCH * 4;
  float* gstats = (float*)ws; ws += 1024;
  unsigned short* Yb = mixb;     // mixbuf dead after gemm-v; gn output reuses it

  wconv_kernel<<<(4 * WELEM / 4) / 256, 256, 0, stream>>>(Wr, Wk, Wv, Wo, Wb);

  const int mgrid = (int)(MD / 1024);
  // r:
  mix_one_kernel<<<mgrid, 256, 0, stream>>>(x, tmr, mixb);
  gemm_bt<1, 1><<<1536, 256, 0, stream>>>(mixb, Wb,             (void*)RKV, NF, 0);
  // k:
  mix_one_kernel<<<mgrid, 256, 0, stream>>>(x, tmk, mixb);
  gemm_bt<0, 1><<<1536, 256, 0, stream>>>(mixb, Wb + WELEM,     (void*)RKV, NF, D_);
  // v:
  mix_one_kernel<<<mgrid, 256, 0, stream>>>(x, tmv, mixb);
  gemm_bt<0, 1><<<1536, 256, 0, stream>>>(mixb, Wb + 2 * WELEM, (void*)RKV, NF, 2 * D_);

  wkv_pass1<<<(CHUNKS * NCH) / 256, 256, 0, stream>>>(RKV, td, sumN, sumD);
  wkv_pass2<<<NCH / 256, 256, 0, stream>>>(sumN, sumD, td, gstats);
  wkv_pass3<<<(CHUNKS * NCH) / 256, 256, 0, stream>>>(RKV, td, tf, sumN, sumD,
                                                      gstats, gstats + 96);
  gn_kernel<<<mgrid, 256, 0, stream>>>(RKV, gstats, gstats + 96, gw, gb, Yb);

  gemm_bt<0, 0><<<1536, 256, 0, stream>>>(Yb, Wb + 3 * WELEM, (void*)out, D_, 0);
}